// Round 4
// baseline (346.641 us; speedup 1.0000x reference)
//
#include <hip/hip_runtime.h>
#include <math.h>

#define B_TOT 4096
#define T_LEN 200
#define C_IN  16
#define HH    112
#define THR   896     // 14 waves
#define NB    16      // batches per block (= MFMA M)
#define EPS   1e-5f
#define SBLK  256     // stats kernel blocks

typedef _Float16 half8  __attribute__((ext_vector_type(8)));
typedef float    f32x4  __attribute__((ext_vector_type(4)));

#define L2E 1.4426950408889634f
#define FLUSH_MIN 6.103515625e-05f   // fp16 min normal

// Split fp32 into fp16 hi + 2^12-scaled fp16 lo (W-side only).
__device__ __forceinline__ void split16(float v, _Float16 &hi, _Float16 &lo) {
    _Float16 h = (_Float16)v;
    float hf = (float)h;
    if (__builtin_fabsf(hf) < FLUSH_MIN) { h = (_Float16)0.0f; hf = 0.0f; }
    hi = h;
    lo = (_Float16)((v - hf) * 4096.0f);
}

// fp16 cast with denormal flush (A-side single-plane).
__device__ __forceinline__ _Float16 to16(float v) {
    _Float16 h = (_Float16)v;
    if (__builtin_fabsf(v) < FLUSH_MIN) h = (_Float16)0.0f;
    return h;
}

// ---------------- Kernel 1: deterministic per-channel partial sums ----------------
__global__ void stats_kernel(const float* __restrict__ x, float* __restrict__ ws) {
    __shared__ float sm[4][4][8];
    const int tid = threadIdx.x;
    const float4* __restrict__ x4 = (const float4*)x;
    const int total  = B_TOT * T_LEN * C_IN / 4;
    const int stride = SBLK * 256;
    const int i0 = blockIdx.x * 256 + tid;

    float s0=0.f,s1=0.f,s2=0.f,s3=0.f;
    float q0=0.f,q1=0.f,q2=0.f,q3=0.f;
    for (int i = i0; i < total; i += stride) {
        float4 v = x4[i];
        s0 += v.x; q0 += v.x*v.x;
        s1 += v.y; q1 += v.y*v.y;
        s2 += v.z; q2 += v.z*v.z;
        s3 += v.w; q3 += v.w*v.w;
    }
    #pragma unroll
    for (int off = 4; off < 64; off <<= 1) {
        s0 += __shfl_xor(s0, off); q0 += __shfl_xor(q0, off);
        s1 += __shfl_xor(s1, off); q1 += __shfl_xor(q1, off);
        s2 += __shfl_xor(s2, off); q2 += __shfl_xor(q2, off);
        s3 += __shfl_xor(s3, off); q3 += __shfl_xor(q3, off);
    }
    const int lane = tid & 63, wave = tid >> 6;
    if (lane < 4) {
        sm[wave][lane][0] = s0; sm[wave][lane][1] = s1;
        sm[wave][lane][2] = s2; sm[wave][lane][3] = s3;
        sm[wave][lane][4] = q0; sm[wave][lane][5] = q1;
        sm[wave][lane][6] = q2; sm[wave][lane][7] = q3;
    }
    __syncthreads();
    if (tid < 32) {
        const int ch = tid & 15, sq = tid >> 4;
        const int grp = ch >> 2, comp = ch & 3;
        float a = 0.f;
        #pragma unroll
        for (int wv = 0; wv < 4; wv++) a += sm[wv][grp][sq * 4 + comp];
        ws[blockIdx.x * 32 + tid] = a;
    }
}

// ---------------- Kernel 2: MFMA LSTM, 14-wave gate-split ----------------
// 256 blocks x 896 threads (14 waves = 7 j-tiles x 2 sides).
//   side 0 (waves 0-6):  gates {i, g}; owns cell state c; cell update + h-write.
//   side 1 (waves 7-13): gates {f, o}; publishes act_f/act_o via LDS; stages x.
// Both sides of a j-tile pair share the identical lane<->(batch,n) D mapping,
// so the exchange is per-lane aligned. 16 MFMAs/wave/step (was 32 on 7 waves):
// same total MFMA work, but 3.5 waves/SIMD (was 1.75) to hide latency.
// Two barriers/step: bar1 = acts published, bar2 = h_t (and x_{t+1}) staged.

#define MFMA_S(s) do {                                                               \
    _Pragma("unroll")                                                                \
    for (int kt = 0; kt < 4; ++kt) {                                                 \
        ch[s] = __builtin_amdgcn_mfma_f32_16x16x32_f16(ah[kt], wHI[s][kt], ch[s], 0, 0, 0); \
        cl[s] = __builtin_amdgcn_mfma_f32_16x16x32_f16(ah[kt], wLO[s][kt], cl[s], 0, 0, 0); \
    }                                                                                \
} while (0)

#define ACT_S(s) do {                                                                \
    _Pragma("unroll")                                                                \
    for (int r = 0; r < 4; ++r) {                                                    \
        float a_ = fmaf(ch[s][r], k1v[s], bpre[s]);                                  \
        a_ = fmaf(cl[s][r], k1sv[s], a_);                                            \
        const float e_  = __builtin_amdgcn_exp2f(a_);                                \
        const float rr_ = __builtin_amdgcn_rcpf(1.f + e_);                           \
        act[s][r] = fmaf(mgv[s], rr_, dgcv[s]);                                      \
    }                                                                                \
} while (0)

__global__ __launch_bounds__(896, 1) void lstm_kernel(
    const float* __restrict__ x,
    const float* __restrict__ gamma, const float* __restrict__ beta,
    const float* __restrict__ W_ih,  const float* __restrict__ W_hh,
    const float* __restrict__ b_ih,  const float* __restrict__ b_hh,
    const float* __restrict__ W_fc,  const float* __restrict__ b_fc,
    const float* __restrict__ ws,    float* __restrict__ out)
{
    __shared__ float stats_s[32];
    __shared__ float scale_s[16], shift_s[16];
    __shared__ __align__(16) _Float16 vbuf[2][4][64][8]; // [parity][kt][lane][8]
    __shared__ float xact[2][4][7][64];                  // [f/o][r][jtile][lane] lane-stride 4B: conflict-free
    __shared__ __align__(16) float hfinal[NB][HH];

    const int u    = threadIdx.x;
    const int lane = u & 63;
    const int wv   = u >> 6;          // 0..13
    const int side = (wv >= 7);       // 0: i,g + cell/h; 1: f,o + x stage
    const int wv2  = side ? wv - 7 : wv;   // j-tile 0..6
    const int nloc = lane & 15;
    const int q    = lane >> 4;       // 0..3
    const int b0   = blockIdx.x * NB;

    // --- BN stats (deterministic fixed-order reduction) ---
    if (u < 32) {
        float a = 0.f;
        for (int blk = 0; blk < SBLK; ++blk) a += ws[blk * 32 + u];
        stats_s[u] = a;
    }
    __syncthreads();
    if (u < 16) {
        const float N = (float)B_TOT * (float)T_LEN;
        const float mean = stats_s[u] / N;
        const float var  = stats_s[16 + u] / N - mean * mean;
        const float sc   = gamma[u] * rsqrtf(var + EPS);
        scale_s[u] = sc;
        shift_s[u] = beta[u] - mean * sc;
    }
    for (int i = u; i < (int)(sizeof(vbuf) / 4); i += THR) ((int*)vbuf)[i] = 0;
    __syncthreads();

    // --- Register-resident weight fragments: 2 gates per wave ---
    const int gates0 = side ? 1 : 0;   // f : i
    const int gates1 = side ? 3 : 2;   // o : g
    half8 wHI[2][4], wLO[2][4];
    float bpre[2], mgv[2], k1v[2], k1sv[2], dgcv[2];
    #pragma unroll
    for (int s = 0; s < 2; ++s) {
        const int nt = s ? gates1 : gates0;
        const int n = nt * HH + wv2 * 16 + nloc;
        #pragma unroll
        for (int kt = 0; kt < 4; ++kt) {
            const int kb = kt * 32 + q * 8;    // never straddles k=112
            float wtmp[8];
            if (kb < HH) {
                float4 aa = *(const float4*)&W_hh[n * HH + kb];
                float4 bb = *(const float4*)&W_hh[n * HH + kb + 4];
                wtmp[0]=aa.x; wtmp[1]=aa.y; wtmp[2]=aa.z; wtmp[3]=aa.w;
                wtmp[4]=bb.x; wtmp[5]=bb.y; wtmp[6]=bb.z; wtmp[7]=bb.w;
            } else {
                const int c0 = kb - HH;
                float4 aa = *(const float4*)&W_ih[n * C_IN + c0];
                float4 bb = *(const float4*)&W_ih[n * C_IN + c0 + 4];
                wtmp[0]=aa.x*scale_s[c0+0]; wtmp[1]=aa.y*scale_s[c0+1];
                wtmp[2]=aa.z*scale_s[c0+2]; wtmp[3]=aa.w*scale_s[c0+3];
                wtmp[4]=bb.x*scale_s[c0+4]; wtmp[5]=bb.y*scale_s[c0+5];
                wtmp[6]=bb.z*scale_s[c0+6]; wtmp[7]=bb.w*scale_s[c0+7];
            }
            #pragma unroll
            for (int jj = 0; jj < 8; ++jj) {
                _Float16 th, tl;
                split16(wtmp[jj], th, tl);
                wHI[s][kt][jj] = th;
                wLO[s][kt][jj] = tl;
            }
        }
        float bb2 = b_ih[n] + b_hh[n];
        #pragma unroll
        for (int c = 0; c < C_IN; ++c) bb2 += W_ih[n * C_IN + c] * shift_s[c];
        const float mg = (nt == 2) ? 2.f : 1.f;
        mgv[s]  = mg;
        k1v[s]  = -mg * L2E;
        k1sv[s] = k1v[s] * (1.f / 4096.f);
        dgcv[s] = 1.f - mg;
        bpre[s] = bb2 * k1v[s];
    }

    // --- h write-back mapping (side 0; A-fragment address for column jcol) ---
    const int jcol = wv2 * 16 + nloc;         // 0..111
    const int kt_h = jcol >> 5;
    const int jh   = jcol & 7;
    const int qh16 = ((jcol >> 3) & 3) * 16;  // lane' = b + qh16

    // --- x loader mapping: side-1 threads 0..255 of that side, one element each ---
    const int u2 = side ? (u - 448) : 0;      // 0..447 on side 1
    const int xb = u2 >> 4;                   // batch 0..15
    const int xc = u2 & 15;                   // channel 0..15
    const size_t xbase = (size_t)(b0 + xb) * (T_LEN * C_IN) + xc;
    const int ltx = xb + 16 * (((HH + xc) >> 3) & 3);   // A-frag lane for k=112+xc
    const int jx  = xc & 7;
    const bool xldr = side && (u2 < 256);

    float xval = 0.f;
    if (xldr) {
        xval = x[xbase];                      // x at t=0 -> parity 0
        vbuf[0][3][ltx][jx] = to16(xval);
    }
    __syncthreads();

    float creg[4] = {0.f, 0.f, 0.f, 0.f};     // cell state: side 0 only

    for (int step = 0; step < T_LEN; ++step) {
        const int p = step & 1;
        if (xldr && step + 1 < T_LEN)
            xval = x[xbase + (size_t)(step + 1) * C_IN];   // prefetch next x

        // A-fragments for this step (all 4 k-tiles)
        half8 ah[4];
        #pragma unroll
        for (int kt = 0; kt < 4; ++kt)
            ah[kt] = *(const half8*)&vbuf[p][kt][lane][0];

        f32x4 ch[2], cl[2];
        #pragma unroll
        for (int s = 0; s < 2; ++s) {
            ch[s] = (f32x4){0.f, 0.f, 0.f, 0.f};
            cl[s] = (f32x4){0.f, 0.f, 0.f, 0.f};
        }

        float act[2][4];
        MFMA_S(0);
        MFMA_S(1);  ACT_S(0);
        ACT_S(1);

        // side 1 publishes f,o activations (lane-aligned with side 0's mapping)
        if (side) {
            #pragma unroll
            for (int r = 0; r < 4; ++r) {
                xact[0][r][wv2][lane] = act[0][r];   // f
                xact[1][r][wv2][lane] = act[1][r];   // o
            }
        }
        __syncthreads();   // bar1: acts visible; vbuf[p] fully consumed

        const bool last = (step + 1 == T_LEN);
        if (!side) {
            // cell update + h: act[0]=i, act[1]=g, remote f,o
            #pragma unroll
            for (int r = 0; r < 4; ++r) {
                const float af = xact[0][r][wv2][lane];
                const float ao = xact[1][r][wv2][lane];
                const float cn = fmaf(af, creg[r], act[0][r] * act[1][r]);
                creg[r] = cn;
                const float e2 = __builtin_amdgcn_exp2f(cn * (-2.f * L2E));
                const float th = fmaf(2.f, __builtin_amdgcn_rcpf(1.f + e2), -1.f);
                const float hv = ao * th;
                if (!last) vbuf[1 - p][kt_h][q * 4 + r + qh16][jh] = to16(hv);
                else       hfinal[q * 4 + r][jcol] = hv;
            }
        } else if (xldr && !last) {
            vbuf[1 - p][3][ltx][jx] = to16(xval);   // stage x_{t+1} in idle tail
        }
        __syncthreads();   // bar2: h_t (and x_{t+1}) ready
    }

    // --- FC head ---
    if (u < NB * 6) {
        const int b = u / 6, o = u - b * 6;
        float a = b_fc[o];
        for (int j = 0; j < HH; ++j) a += hfinal[b][j] * W_fc[o * HH + j];
        out[(size_t)(b0 + b) * 6 + o] = tanhf(a);
    }
}

extern "C" void kernel_launch(void* const* d_in, const int* in_sizes, int n_in,
                              void* d_out, int out_size, void* d_ws, size_t ws_size,
                              hipStream_t stream) {
    const float* x     = (const float*)d_in[0];
    const float* gamma = (const float*)d_in[1];
    const float* beta  = (const float*)d_in[2];
    const float* W_ih  = (const float*)d_in[3];
    const float* W_hh  = (const float*)d_in[4];
    const float* b_ih  = (const float*)d_in[5];
    const float* b_hh  = (const float*)d_in[6];
    const float* W_fc  = (const float*)d_in[7];
    const float* b_fc  = (const float*)d_in[8];
    float* out = (float*)d_out;
    float* ws  = (float*)d_ws;

    stats_kernel<<<SBLK, 256, 0, stream>>>(x, ws);
    lstm_kernel<<<B_TOT / NB, THR, 0, stream>>>(x, gamma, beta, W_ih, W_hh,
                                                b_ih, b_hh, W_fc, b_fc, ws, out);
}

// Round 5
// 321.243 us; speedup vs baseline: 1.0791x; 1.0791x over previous
//
#include <hip/hip_runtime.h>
#include <math.h>

#define B_TOT 4096
#define T_LEN 200
#define C_IN  16
#define HH    112
#define G4    448
#define NB    16      // batches per block (= MFMA M)
#define EPS   1e-5f
#define SBLK  256     // stats kernel blocks
#define STHR  1024    // stats kernel threads (16 waves: latency hiding)

typedef _Float16 half8  __attribute__((ext_vector_type(8)));
typedef float    f32x4  __attribute__((ext_vector_type(4)));

#define L2E 1.4426950408889634f
#define FLUSH_MIN 6.103515625e-05f   // fp16 min normal

// Split fp32 into fp16 hi + 2^12-scaled fp16 lo (W-side only).
__device__ __forceinline__ void split16(float v, _Float16 &hi, _Float16 &lo) {
    _Float16 h = (_Float16)v;
    float hf = (float)h;
    if (__builtin_fabsf(hf) < FLUSH_MIN) { h = (_Float16)0.0f; hf = 0.0f; }
    hi = h;
    lo = (_Float16)((v - hf) * 4096.0f);
}

// fp16 cast with denormal flush (A-side single-plane).
__device__ __forceinline__ _Float16 to16(float v) {
    _Float16 h = (_Float16)v;
    if (__builtin_fabsf(v) < FLUSH_MIN) h = (_Float16)0.0f;
    return h;
}

// ---------------- Kernel 1: deterministic per-channel partial sums ----------------
// 256 blocks x 1024 threads (16 waves/CU). Was 256 threads = 4 waves/CU ->
// latency-bound at ~1 TB/s (~45 us). 4x TLP pushes toward BW roofline.
// ws layout [SBLK][32] and the per-block fixed reduction order are unchanged,
// so downstream stats are bitwise identical.
__global__ __launch_bounds__(STHR) void stats_kernel(const float* __restrict__ x,
                                                     float* __restrict__ ws) {
    __shared__ float sm[16][4][8];
    const int tid = threadIdx.x;
    const float4* __restrict__ x4 = (const float4*)x;
    const int total  = B_TOT * T_LEN * C_IN / 4;
    const int stride = SBLK * STHR;
    const int i0 = blockIdx.x * STHR + tid;

    float s0=0.f,s1=0.f,s2=0.f,s3=0.f;
    float q0=0.f,q1=0.f,q2=0.f,q3=0.f;
    for (int i = i0; i < total; i += stride) {
        float4 v = x4[i];
        s0 += v.x; q0 += v.x*v.x;
        s1 += v.y; q1 += v.y*v.y;
        s2 += v.z; q2 += v.z*v.z;
        s3 += v.w; q3 += v.w*v.w;
    }
    #pragma unroll
    for (int off = 4; off < 64; off <<= 1) {
        s0 += __shfl_xor(s0, off); q0 += __shfl_xor(q0, off);
        s1 += __shfl_xor(s1, off); q1 += __shfl_xor(q1, off);
        s2 += __shfl_xor(s2, off); q2 += __shfl_xor(q2, off);
        s3 += __shfl_xor(s3, off); q3 += __shfl_xor(q3, off);
    }
    const int lane = tid & 63, wave = tid >> 6;
    if (lane < 4) {
        sm[wave][lane][0] = s0; sm[wave][lane][1] = s1;
        sm[wave][lane][2] = s2; sm[wave][lane][3] = s3;
        sm[wave][lane][4] = q0; sm[wave][lane][5] = q1;
        sm[wave][lane][6] = q2; sm[wave][lane][7] = q3;
    }
    __syncthreads();
    if (tid < 32) {
        const int ch = tid & 15, sq = tid >> 4;
        const int grp = ch >> 2, comp = ch & 3;
        float a = 0.f;
        #pragma unroll
        for (int wv = 0; wv < 16; wv++) a += sm[wv][grp][sq * 4 + comp];
        ws[blockIdx.x * 32 + tid] = a;
    }
}

// ---------------- Kernel 2: MFMA LSTM, one barrier/step ----------------
// (identical to the round-3 kernel: 263 us measured; 7 waves, nt-outer,
//  single-plane A, W hi+lo. Round-4's 14-wave gate-split regressed ->
//  the step is critical-path bound, not TLP bound.)

#define MFMA_NT(nt) do {                                                             \
    _Pragma("unroll")                                                                \
    for (int kt = 0; kt < 4; ++kt) {                                                 \
        ch[nt] = __builtin_amdgcn_mfma_f32_16x16x32_f16(ah[kt], wHI[nt][kt], ch[nt], 0, 0, 0); \
        cl[nt] = __builtin_amdgcn_mfma_f32_16x16x32_f16(ah[kt], wLO[nt][kt], cl[nt], 0, 0, 0); \
    }                                                                                \
} while (0)

#define ACT_NT(nt) do {                                                              \
    const float mg_  = ((nt) == 2) ? 2.f : 1.f;                                      \
    const float k1_  = -mg_ * L2E;                                                   \
    const float k1s_ = k1_ * (1.f / 4096.f);                                         \
    const float dgc_ = 1.f - mg_;                                                    \
    _Pragma("unroll")                                                                \
    for (int r = 0; r < 4; ++r) {                                                    \
        float a_ = fmaf(ch[nt][r], k1_, bpre[nt]);                                   \
        a_ = fmaf(cl[nt][r], k1s_, a_);                                              \
        const float e_  = __builtin_amdgcn_exp2f(a_);                                \
        const float rr_ = __builtin_amdgcn_rcpf(1.f + e_);                           \
        act[nt][r] = fmaf(mg_, rr_, dgc_);                                           \
    }                                                                                \
} while (0)

__global__ __launch_bounds__(448, 2) void lstm_kernel(
    const float* __restrict__ x,
    const float* __restrict__ gamma, const float* __restrict__ beta,
    const float* __restrict__ W_ih,  const float* __restrict__ W_hh,
    const float* __restrict__ b_ih,  const float* __restrict__ b_hh,
    const float* __restrict__ W_fc,  const float* __restrict__ b_fc,
    const float* __restrict__ ws,    float* __restrict__ out)
{
    __shared__ float stats_s[32];
    __shared__ float scale_s[16], shift_s[16];
    __shared__ __align__(16) _Float16 vbuf[2][4][64][8]; // [parity][kt][lane][8] (hi plane only)
    __shared__ __align__(16) float hfinal[NB][HH];

    const int u    = threadIdx.x;
    const int lane = u & 63;
    const int wv   = u >> 6;          // wave = j-tile 0..6
    const int nloc = lane & 15;
    const int q    = lane >> 4;       // 0..3
    const int b0   = blockIdx.x * NB;

    // --- BN stats (deterministic fixed-order reduction) ---
    if (u < 32) {
        float a = 0.f;
        for (int blk = 0; blk < SBLK; ++blk) a += ws[blk * 32 + u];
        stats_s[u] = a;
    }
    __syncthreads();
    if (u < 16) {
        const float N = (float)B_TOT * (float)T_LEN;
        const float mean = stats_s[u] / N;
        const float var  = stats_s[16 + u] / N - mean * mean;
        const float sc   = gamma[u] * rsqrtf(var + EPS);
        scale_s[u] = sc;
        shift_s[u] = beta[u] - mean * sc;
    }
    for (int i = u; i < (int)(sizeof(vbuf) / 4); i += G4) ((int*)vbuf)[i] = 0;
    __syncthreads();

    // --- Register-resident weight fragments (one-time) ---
    // B-fragment: lane (nloc,q) holds W_cat[n][k = kt*32 + q*8 + jj]
    half8 wHI[4][4], wLO[4][4];
    float bpre[4];                    // bias * k1 (activation-prescaled)
    #pragma unroll
    for (int nt = 0; nt < 4; ++nt) {  // nt == gate index
        const int n = nt * HH + wv * 16 + nloc;
        #pragma unroll
        for (int kt = 0; kt < 4; ++kt) {
            const int kb = kt * 32 + q * 8;    // never straddles k=112
            float wtmp[8];
            if (kb < HH) {
                float4 aa = *(const float4*)&W_hh[n * HH + kb];
                float4 bb = *(const float4*)&W_hh[n * HH + kb + 4];
                wtmp[0]=aa.x; wtmp[1]=aa.y; wtmp[2]=aa.z; wtmp[3]=aa.w;
                wtmp[4]=bb.x; wtmp[5]=bb.y; wtmp[6]=bb.z; wtmp[7]=bb.w;
            } else {
                const int c0 = kb - HH;
                float4 aa = *(const float4*)&W_ih[n * C_IN + c0];
                float4 bb = *(const float4*)&W_ih[n * C_IN + c0 + 4];
                wtmp[0]=aa.x*scale_s[c0+0]; wtmp[1]=aa.y*scale_s[c0+1];
                wtmp[2]=aa.z*scale_s[c0+2]; wtmp[3]=aa.w*scale_s[c0+3];
                wtmp[4]=bb.x*scale_s[c0+4]; wtmp[5]=bb.y*scale_s[c0+5];
                wtmp[6]=bb.z*scale_s[c0+6]; wtmp[7]=bb.w*scale_s[c0+7];
            }
            #pragma unroll
            for (int jj = 0; jj < 8; ++jj) {
                _Float16 th, tl;
                split16(wtmp[jj], th, tl);
                wHI[nt][kt][jj] = th;
                wLO[nt][kt][jj] = tl;
            }
        }
        float bb2 = b_ih[n] + b_hh[n];
        #pragma unroll
        for (int c = 0; c < C_IN; ++c) bb2 += W_ih[n * C_IN + c] * shift_s[c];
        const float mg = (nt == 2) ? 2.f : 1.f;
        bpre[nt] = bb2 * (-mg * L2E);
    }

    // --- h write-back mapping (A-fragment address for column jcol) ---
    const int jcol = wv * 16 + nloc;          // 0..111
    const int kt_h = jcol >> 5;
    const int jh   = jcol & 7;
    const int qh16 = ((jcol >> 3) & 3) * 16;  // lane' = b + qh16

    // --- x loader mapping: 256 threads (waves 0-3), ONE element each ---
    const int xb = u >> 4;                    // batch 0..15
    const int xc = u & 15;                    // channel 0..15
    const size_t xbase = (size_t)(b0 + xb) * (T_LEN * C_IN) + xc;
    const int ltx = xb + 16 * (((HH + xc) >> 3) & 3);   // A-frag lane for k=112+xc
    const int jx  = xc & 7;

    float xval;
    if (u < 256) {
        xval = x[xbase];                      // x at t=0 -> parity 0
        vbuf[0][3][ltx][jx] = to16(xval);
    }
    __syncthreads();

    float creg[4] = {0.f, 0.f, 0.f, 0.f};

    for (int step = 0; step < T_LEN; ++step) {
        const int p = step & 1;
        if (u < 256 && step + 1 < T_LEN)
            xval = x[xbase + (size_t)(step + 1) * C_IN];   // prefetch next x

        // A-fragments for this step (all 4 k-tiles, single plane)
        half8 ah[4];
        #pragma unroll
        for (int kt = 0; kt < 4; ++kt)
            ah[kt] = *(const half8*)&vbuf[p][kt][lane][0];

        f32x4 ch[4], cl[4];
        #pragma unroll
        for (int nt = 0; nt < 4; ++nt) {
            ch[nt] = (f32x4){0.f, 0.f, 0.f, 0.f};
            cl[nt] = (f32x4){0.f, 0.f, 0.f, 0.f};
        }

        float act[4][4];
        float thc[4];

        // nt-outer pipeline: gate nt's activation VALU overlaps gate nt+1's
        // MFMA issue; cell update (needs i,f,g) overlaps gate-o's MFMAs.
        MFMA_NT(0);
        MFMA_NT(1);  ACT_NT(0);
        MFMA_NT(2);  ACT_NT(1);
        MFMA_NT(3);  ACT_NT(2);
        #pragma unroll
        for (int r = 0; r < 4; ++r) {
            const float cn = fmaf(act[1][r], creg[r], act[0][r] * act[2][r]);
            creg[r] = cn;
            const float e2 = __builtin_amdgcn_exp2f(cn * (-2.f * L2E));
            thc[r] = fmaf(2.f, __builtin_amdgcn_rcpf(1.f + e2), -1.f);
        }
        ACT_NT(3);

        const bool last = (step + 1 == T_LEN);
        #pragma unroll
        for (int r = 0; r < 4; ++r) {
            const float hv = act[3][r] * thc[r];
            if (!last) {
                vbuf[1 - p][kt_h][q * 4 + r + qh16][jh] = to16(hv);
            } else {
                hfinal[q * 4 + r][jcol] = hv;
            }
        }
        if (u < 256 && step + 1 < T_LEN)
            vbuf[1 - p][3][ltx][jx] = to16(xval);
        __syncthreads();
    }

    // --- FC head ---
    if (u < NB * 6) {
        const int b = u / 6, o = u - b * 6;
        float a = b_fc[o];
        for (int j = 0; j < HH; ++j) a += hfinal[b][j] * W_fc[o * HH + j];
        out[(size_t)(b0 + b) * 6 + o] = tanhf(a);
    }
}

extern "C" void kernel_launch(void* const* d_in, const int* in_sizes, int n_in,
                              void* d_out, int out_size, void* d_ws, size_t ws_size,
                              hipStream_t stream) {
    const float* x     = (const float*)d_in[0];
    const float* gamma = (const float*)d_in[1];
    const float* beta  = (const float*)d_in[2];
    const float* W_ih  = (const float*)d_in[3];
    const float* W_hh  = (const float*)d_in[4];
    const float* b_ih  = (const float*)d_in[5];
    const float* b_hh  = (const float*)d_in[6];
    const float* W_fc  = (const float*)d_in[7];
    const float* b_fc  = (const float*)d_in[8];
    float* out = (float*)d_out;
    float* ws  = (float*)d_ws;

    stats_kernel<<<SBLK, STHR, 0, stream>>>(x, ws);
    lstm_kernel<<<B_TOT / NB, 448, 0, stream>>>(x, gamma, beta, W_ih, W_hh,
                                                b_ih, b_hh, W_fc, b_fc, ws, out);
}

// Round 6
// 272.763 us; speedup vs baseline: 1.2709x; 1.1777x over previous
//
#include <hip/hip_runtime.h>
#include <math.h>

#define B_TOT 4096
#define T_LEN 200
#define C_IN  16
#define HH    112
#define G4    448
#define NB    16      // batches per block (= MFMA M)
#define EPS   1e-5f
#define SBLK  256     // stats kernel blocks
#define STHR  1024    // stats kernel threads (16 waves: latency hiding)

typedef _Float16 half8  __attribute__((ext_vector_type(8)));
typedef float    f32x4  __attribute__((ext_vector_type(4)));

#define L2E 1.4426950408889634f
#define FLUSH_MIN 6.103515625e-05f   // fp16 min normal

// fp16 cast with denormal flush (MFMA denormal behavior unverified).
__device__ __forceinline__ _Float16 to16(float v) {
    _Float16 h = (_Float16)v;
    if (__builtin_fabsf(v) < FLUSH_MIN) h = (_Float16)0.0f;
    return h;
}

// ---------------- Kernel 1: deterministic per-channel partial sums ----------------
// 256 blocks x 1024 threads (16 waves/CU) -> latency hidden, ~10 us.
__global__ __launch_bounds__(STHR) void stats_kernel(const float* __restrict__ x,
                                                     float* __restrict__ ws) {
    __shared__ float sm[16][4][8];
    const int tid = threadIdx.x;
    const float4* __restrict__ x4 = (const float4*)x;
    const int total  = B_TOT * T_LEN * C_IN / 4;
    const int stride = SBLK * STHR;
    const int i0 = blockIdx.x * STHR + tid;

    float s0=0.f,s1=0.f,s2=0.f,s3=0.f;
    float q0=0.f,q1=0.f,q2=0.f,q3=0.f;
    for (int i = i0; i < total; i += stride) {
        float4 v = x4[i];
        s0 += v.x; q0 += v.x*v.x;
        s1 += v.y; q1 += v.y*v.y;
        s2 += v.z; q2 += v.z*v.z;
        s3 += v.w; q3 += v.w*v.w;
    }
    #pragma unroll
    for (int off = 4; off < 64; off <<= 1) {
        s0 += __shfl_xor(s0, off); q0 += __shfl_xor(q0, off);
        s1 += __shfl_xor(s1, off); q1 += __shfl_xor(q1, off);
        s2 += __shfl_xor(s2, off); q2 += __shfl_xor(q2, off);
        s3 += __shfl_xor(s3, off); q3 += __shfl_xor(q3, off);
    }
    const int lane = tid & 63, wave = tid >> 6;
    if (lane < 4) {
        sm[wave][lane][0] = s0; sm[wave][lane][1] = s1;
        sm[wave][lane][2] = s2; sm[wave][lane][3] = s3;
        sm[wave][lane][4] = q0; sm[wave][lane][5] = q1;
        sm[wave][lane][6] = q2; sm[wave][lane][7] = q3;
    }
    __syncthreads();
    if (tid < 32) {
        const int ch = tid & 15, sq = tid >> 4;
        const int grp = ch >> 2, comp = ch & 3;
        float a = 0.f;
        #pragma unroll
        for (int wv = 0; wv < 16; wv++) a += sm[wv][grp][sq * 4 + comp];
        ws[blockIdx.x * 32 + tid] = a;
    }
}

// ---------------- Kernel 2: MFMA LSTM, one barrier/step ----------------
// 256 blocks x 448 threads (7 waves). Wave w owns the FOUR GATE TILES of
// j-tile w: n = gate*112 + 16w + nloc. All four share the same D lane
// mapping -> cell update is in-lane, c in registers.
// v_t = [h_{t-1}; x_t] in LDS, A-fragment order, single fp16 plane.
// W is now SINGLE-plane fp16 too (wLO dropped): delta_w rms ~5e-6 ->
// delta_z ~2.3e-5/step/gate, same order as the accepted h-quant noise;
// halves MFMA issue (16/step/wave), removes cl chains + 16 acc-zeros.

#define MFMA_NT(nt) do {                                                             \
    _Pragma("unroll")                                                                \
    for (int kt = 0; kt < 4; ++kt)                                                   \
        ch[nt] = __builtin_amdgcn_mfma_f32_16x16x32_f16(ah[kt], wHI[nt][kt], ch[nt], 0, 0, 0); \
} while (0)

#define ACT_NT(nt) do {                                                              \
    const float mg_  = ((nt) == 2) ? 2.f : 1.f;                                      \
    const float k1_  = -mg_ * L2E;                                                   \
    const float dgc_ = 1.f - mg_;                                                    \
    _Pragma("unroll")                                                                \
    for (int r = 0; r < 4; ++r) {                                                    \
        const float a_  = fmaf(ch[nt][r], k1_, bpre[nt]);                            \
        const float e_  = __builtin_amdgcn_exp2f(a_);                                \
        const float rr_ = __builtin_amdgcn_rcpf(1.f + e_);                           \
        act[nt][r] = fmaf(mg_, rr_, dgc_);                                           \
    }                                                                                \
} while (0)

__global__ __launch_bounds__(448, 2) void lstm_kernel(
    const float* __restrict__ x,
    const float* __restrict__ gamma, const float* __restrict__ beta,
    const float* __restrict__ W_ih,  const float* __restrict__ W_hh,
    const float* __restrict__ b_ih,  const float* __restrict__ b_hh,
    const float* __restrict__ W_fc,  const float* __restrict__ b_fc,
    const float* __restrict__ ws,    float* __restrict__ out)
{
    __shared__ float stats_s[32];
    __shared__ float scale_s[16], shift_s[16];
    __shared__ __align__(16) _Float16 vbuf[2][4][64][8]; // [parity][kt][lane][8]
    __shared__ __align__(16) float hfinal[NB][HH];

    const int u    = threadIdx.x;
    const int lane = u & 63;
    const int wv   = u >> 6;          // wave = j-tile 0..6
    const int nloc = lane & 15;
    const int q    = lane >> 4;       // 0..3
    const int b0   = blockIdx.x * NB;

    // --- BN stats (deterministic fixed-order reduction) ---
    if (u < 32) {
        float a = 0.f;
        for (int blk = 0; blk < SBLK; ++blk) a += ws[blk * 32 + u];
        stats_s[u] = a;
    }
    __syncthreads();
    if (u < 16) {
        const float N = (float)B_TOT * (float)T_LEN;
        const float mean = stats_s[u] / N;
        const float var  = stats_s[16 + u] / N - mean * mean;
        const float sc   = gamma[u] * rsqrtf(var + EPS);
        scale_s[u] = sc;
        shift_s[u] = beta[u] - mean * sc;
    }
    for (int i = u; i < (int)(sizeof(vbuf) / 4); i += G4) ((int*)vbuf)[i] = 0;
    __syncthreads();

    // --- Register-resident weight fragments (one-time, fp16 single plane) ---
    // B-fragment: lane (nloc,q) holds W_cat[n][k = kt*32 + q*8 + jj]
    half8 wHI[4][4];
    float bpre[4];                    // bias * k1 (activation-prescaled)
    #pragma unroll
    for (int nt = 0; nt < 4; ++nt) {  // nt == gate index
        const int n = nt * HH + wv * 16 + nloc;
        #pragma unroll
        for (int kt = 0; kt < 4; ++kt) {
            const int kb = kt * 32 + q * 8;    // never straddles k=112
            float wtmp[8];
            if (kb < HH) {
                float4 aa = *(const float4*)&W_hh[n * HH + kb];
                float4 bb = *(const float4*)&W_hh[n * HH + kb + 4];
                wtmp[0]=aa.x; wtmp[1]=aa.y; wtmp[2]=aa.z; wtmp[3]=aa.w;
                wtmp[4]=bb.x; wtmp[5]=bb.y; wtmp[6]=bb.z; wtmp[7]=bb.w;
            } else {
                const int c0 = kb - HH;
                float4 aa = *(const float4*)&W_ih[n * C_IN + c0];
                float4 bb = *(const float4*)&W_ih[n * C_IN + c0 + 4];
                wtmp[0]=aa.x*scale_s[c0+0]; wtmp[1]=aa.y*scale_s[c0+1];
                wtmp[2]=aa.z*scale_s[c0+2]; wtmp[3]=aa.w*scale_s[c0+3];
                wtmp[4]=bb.x*scale_s[c0+4]; wtmp[5]=bb.y*scale_s[c0+5];
                wtmp[6]=bb.z*scale_s[c0+6]; wtmp[7]=bb.w*scale_s[c0+7];
            }
            #pragma unroll
            for (int jj = 0; jj < 8; ++jj) wHI[nt][kt][jj] = to16(wtmp[jj]);
        }
        float bb2 = b_ih[n] + b_hh[n];
        #pragma unroll
        for (int c = 0; c < C_IN; ++c) bb2 += W_ih[n * C_IN + c] * shift_s[c];
        const float mg = (nt == 2) ? 2.f : 1.f;
        bpre[nt] = bb2 * (-mg * L2E);
    }

    // --- h write-back mapping (A-fragment address for column jcol) ---
    const int jcol = wv * 16 + nloc;          // 0..111
    const int kt_h = jcol >> 5;
    const int jh   = jcol & 7;
    const int qh16 = ((jcol >> 3) & 3) * 16;  // lane' = b + qh16

    // --- x loader mapping: 256 threads (waves 0-3), ONE element each ---
    const int xb = u >> 4;                    // batch 0..15
    const int xc = u & 15;                    // channel 0..15
    const size_t xbase = (size_t)(b0 + xb) * (T_LEN * C_IN) + xc;
    const int ltx = xb + 16 * (((HH + xc) >> 3) & 3);   // A-frag lane for k=112+xc
    const int jx  = xc & 7;

    float xval;
    if (u < 256) {
        xval = x[xbase];                      // x at t=0 -> parity 0
        vbuf[0][3][ltx][jx] = to16(xval);
    }
    __syncthreads();

    float creg[4] = {0.f, 0.f, 0.f, 0.f};

    for (int step = 0; step < T_LEN; ++step) {
        const int p = step & 1;
        if (u < 256 && step + 1 < T_LEN)
            xval = x[xbase + (size_t)(step + 1) * C_IN];   // prefetch next x

        // A-fragments for this step (all 4 k-tiles, single plane)
        half8 ah[4];
        #pragma unroll
        for (int kt = 0; kt < 4; ++kt)
            ah[kt] = *(const half8*)&vbuf[p][kt][lane][0];

        f32x4 ch[4];
        #pragma unroll
        for (int nt = 0; nt < 4; ++nt)
            ch[nt] = (f32x4){0.f, 0.f, 0.f, 0.f};

        float act[4][4];
        float thc[4];

        // nt-outer pipeline: gate nt's activation VALU overlaps gate nt+1's
        // MFMA issue; cell update (needs i,f,g) overlaps gate-o's MFMAs.
        MFMA_NT(0);
        MFMA_NT(1);  ACT_NT(0);
        MFMA_NT(2);  ACT_NT(1);
        MFMA_NT(3);  ACT_NT(2);
        #pragma unroll
        for (int r = 0; r < 4; ++r) {
            const float cn = fmaf(act[1][r], creg[r], act[0][r] * act[2][r]);
            creg[r] = cn;
            const float e2 = __builtin_amdgcn_exp2f(cn * (-2.f * L2E));
            thc[r] = fmaf(2.f, __builtin_amdgcn_rcpf(1.f + e2), -1.f);
        }
        ACT_NT(3);

        const bool last = (step + 1 == T_LEN);
        #pragma unroll
        for (int r = 0; r < 4; ++r) {
            const float hv = act[3][r] * thc[r];
            if (!last) {
                vbuf[1 - p][kt_h][q * 4 + r + qh16][jh] = to16(hv);
            } else {
                hfinal[q * 4 + r][jcol] = hv;
            }
        }
        if (u < 256 && step + 1 < T_LEN)
            vbuf[1 - p][3][ltx][jx] = to16(xval);
        __syncthreads();
    }

    // --- FC head ---
    if (u < NB * 6) {
        const int b = u / 6, o = u - b * 6;
        float a = b_fc[o];
        for (int j = 0; j < HH; ++j) a += hfinal[b][j] * W_fc[o * HH + j];
        out[(size_t)(b0 + b) * 6 + o] = tanhf(a);
    }
}

extern "C" void kernel_launch(void* const* d_in, const int* in_sizes, int n_in,
                              void* d_out, int out_size, void* d_ws, size_t ws_size,
                              hipStream_t stream) {
    const float* x     = (const float*)d_in[0];
    const float* gamma = (const float*)d_in[1];
    const float* beta  = (const float*)d_in[2];
    const float* W_ih  = (const float*)d_in[3];
    const float* W_hh  = (const float*)d_in[4];
    const float* b_ih  = (const float*)d_in[5];
    const float* b_hh  = (const float*)d_in[6];
    const float* W_fc  = (const float*)d_in[7];
    const float* b_fc  = (const float*)d_in[8];
    float* out = (float*)d_out;
    float* ws  = (float*)d_ws;

    stats_kernel<<<SBLK, STHR, 0, stream>>>(x, ws);
    lstm_kernel<<<B_TOT / NB, 448, 0, stream>>>(x, gamma, beta, W_ih, W_hh,
                                                b_ih, b_hh, W_fc, b_fc, ws, out);
}

// Round 7
// 259.774 us; speedup vs baseline: 1.3344x; 1.0500x over previous
//
#include <hip/hip_runtime.h>
#include <math.h>

#define B_TOT 4096
#define T_LEN 200
#define C_IN  16
#define HH    112
#define G4    448
#define NB    16      // batches per block (= MFMA M)
#define EPS   1e-5f
#define SBLK  256     // stats kernel blocks
#define STHR  1024    // stats kernel threads (16 waves: latency hiding)

typedef _Float16 half8  __attribute__((ext_vector_type(8)));
typedef float    f32x4  __attribute__((ext_vector_type(4)));

#define L2E 1.4426950408889634f
#define FLUSH_MIN 6.103515625e-05f   // fp16 min normal

// fp16 cast with denormal flush — one-time weight conversion only.
__device__ __forceinline__ _Float16 to16f(float v) {
    _Float16 h = (_Float16)v;
    if (__builtin_fabsf(v) < FLUSH_MIN) h = (_Float16)0.0f;
    return h;
}

// ---------------- Kernel 1: deterministic per-channel partial sums ----------------
// 256 blocks x 1024 threads (16 waves/CU) -> latency hidden, ~10 us.
__global__ __launch_bounds__(STHR) void stats_kernel(const float* __restrict__ x,
                                                     float* __restrict__ ws) {
    __shared__ float sm[16][4][8];
    const int tid = threadIdx.x;
    const float4* __restrict__ x4 = (const float4*)x;
    const int total  = B_TOT * T_LEN * C_IN / 4;
    const int stride = SBLK * STHR;
    const int i0 = blockIdx.x * STHR + tid;

    float s0=0.f,s1=0.f,s2=0.f,s3=0.f;
    float q0=0.f,q1=0.f,q2=0.f,q3=0.f;
    for (int i = i0; i < total; i += stride) {
        float4 v = x4[i];
        s0 += v.x; q0 += v.x*v.x;
        s1 += v.y; q1 += v.y*v.y;
        s2 += v.z; q2 += v.z*v.z;
        s3 += v.w; q3 += v.w*v.w;
    }
    #pragma unroll
    for (int off = 4; off < 64; off <<= 1) {
        s0 += __shfl_xor(s0, off); q0 += __shfl_xor(q0, off);
        s1 += __shfl_xor(s1, off); q1 += __shfl_xor(q1, off);
        s2 += __shfl_xor(s2, off); q2 += __shfl_xor(q2, off);
        s3 += __shfl_xor(s3, off); q3 += __shfl_xor(q3, off);
    }
    const int lane = tid & 63, wave = tid >> 6;
    if (lane < 4) {
        sm[wave][lane][0] = s0; sm[wave][lane][1] = s1;
        sm[wave][lane][2] = s2; sm[wave][lane][3] = s3;
        sm[wave][lane][4] = q0; sm[wave][lane][5] = q1;
        sm[wave][lane][6] = q2; sm[wave][lane][7] = q3;
    }
    __syncthreads();
    if (tid < 32) {
        const int ch = tid & 15, sq = tid >> 4;
        const int grp = ch >> 2, comp = ch & 3;
        float a = 0.f;
        #pragma unroll
        for (int wv = 0; wv < 16; wv++) a += sm[wv][grp][sq * 4 + comp];
        ws[blockIdx.x * 32 + tid] = a;
    }
}

// ---------------- Kernel 2: MFMA LSTM, one barrier/step ----------------
// 256 blocks x 448 threads (7 waves). Wave w owns the FOUR GATE TILES of
// j-tile w: n = gate*112 + 16w + nloc. Cell update in-lane, c in registers.
// v_t = [h_{t-1}; x_t] in LDS, A-fragment order, single fp16 plane.
// VALU-trim round: weights PRE-SCALED by k1 = -mg*L2E and accumulator
// initialized to the pre-scaled bias, so the MFMA output IS the finished
// exp2 argument (deletes the per-element fma pass). Sigmoid gates skip the
// final fma (act = rcp directly); per-step fp16 casts skip the denormal
// flush (one-time W conversion keeps it).

#define MFMA_NT(nt) do {                                                             \
    _Pragma("unroll")                                                                \
    for (int kt = 0; kt < 4; ++kt)                                                   \
        ch[nt] = __builtin_amdgcn_mfma_f32_16x16x32_f16(ah[kt], wHI[nt][kt], ch[nt], 0, 0, 0); \
} while (0)

#define ACT_NT(nt) do {                                                              \
    _Pragma("unroll")                                                                \
    for (int r = 0; r < 4; ++r) {                                                    \
        const float e_  = __builtin_amdgcn_exp2f(ch[nt][r]);                         \
        const float rr_ = __builtin_amdgcn_rcpf(1.f + e_);                           \
        act[nt][r] = ((nt) == 2) ? fmaf(2.f, rr_, -1.f) : rr_;                       \
    }                                                                                \
} while (0)

__global__ __launch_bounds__(448, 2) void lstm_kernel(
    const float* __restrict__ x,
    const float* __restrict__ gamma, const float* __restrict__ beta,
    const float* __restrict__ W_ih,  const float* __restrict__ W_hh,
    const float* __restrict__ b_ih,  const float* __restrict__ b_hh,
    const float* __restrict__ W_fc,  const float* __restrict__ b_fc,
    const float* __restrict__ ws,    float* __restrict__ out)
{
    __shared__ float stats_s[32];
    __shared__ float scale_s[16], shift_s[16];
    __shared__ __align__(16) _Float16 vbuf[2][4][64][8]; // [parity][kt][lane][8]
    __shared__ __align__(16) float hfinal[NB][HH];

    const int u    = threadIdx.x;
    const int lane = u & 63;
    const int wv   = u >> 6;          // wave = j-tile 0..6
    const int nloc = lane & 15;
    const int q    = lane >> 4;       // 0..3
    const int b0   = blockIdx.x * NB;

    // --- BN stats (deterministic fixed-order reduction) ---
    if (u < 32) {
        float a = 0.f;
        for (int blk = 0; blk < SBLK; ++blk) a += ws[blk * 32 + u];
        stats_s[u] = a;
    }
    __syncthreads();
    if (u < 16) {
        const float N = (float)B_TOT * (float)T_LEN;
        const float mean = stats_s[u] / N;
        const float var  = stats_s[16 + u] / N - mean * mean;
        const float sc   = gamma[u] * rsqrtf(var + EPS);
        scale_s[u] = sc;
        shift_s[u] = beta[u] - mean * sc;
    }
    for (int i = u; i < (int)(sizeof(vbuf) / 4); i += G4) ((int*)vbuf)[i] = 0;
    __syncthreads();

    // --- Register-resident weight fragments (one-time, fp16, k1-prescaled) ---
    // B-fragment: lane (nloc,q) holds k1[nt] * W_cat[n][k = kt*32 + q*8 + jj]
    half8 wHI[4][4];
    float bpre[4];                    // k1-prescaled bias (= accumulator init)
    #pragma unroll
    for (int nt = 0; nt < 4; ++nt) {  // nt == gate index
        const int n = nt * HH + wv * 16 + nloc;
        const float mg = (nt == 2) ? 2.f : 1.f;
        const float k1 = -mg * L2E;
        #pragma unroll
        for (int kt = 0; kt < 4; ++kt) {
            const int kb = kt * 32 + q * 8;    // never straddles k=112
            float wtmp[8];
            if (kb < HH) {
                float4 aa = *(const float4*)&W_hh[n * HH + kb];
                float4 bb = *(const float4*)&W_hh[n * HH + kb + 4];
                wtmp[0]=aa.x; wtmp[1]=aa.y; wtmp[2]=aa.z; wtmp[3]=aa.w;
                wtmp[4]=bb.x; wtmp[5]=bb.y; wtmp[6]=bb.z; wtmp[7]=bb.w;
            } else {
                const int c0 = kb - HH;
                float4 aa = *(const float4*)&W_ih[n * C_IN + c0];
                float4 bb = *(const float4*)&W_ih[n * C_IN + c0 + 4];
                wtmp[0]=aa.x*scale_s[c0+0]; wtmp[1]=aa.y*scale_s[c0+1];
                wtmp[2]=aa.z*scale_s[c0+2]; wtmp[3]=aa.w*scale_s[c0+3];
                wtmp[4]=bb.x*scale_s[c0+4]; wtmp[5]=bb.y*scale_s[c0+5];
                wtmp[6]=bb.z*scale_s[c0+6]; wtmp[7]=bb.w*scale_s[c0+7];
            }
            #pragma unroll
            for (int jj = 0; jj < 8; ++jj) wHI[nt][kt][jj] = to16f(k1 * wtmp[jj]);
        }
        float bb2 = b_ih[n] + b_hh[n];
        #pragma unroll
        for (int c = 0; c < C_IN; ++c) bb2 += W_ih[n * C_IN + c] * shift_s[c];
        bpre[nt] = bb2 * k1;
    }

    // --- h write-back mapping (A-fragment address for column jcol) ---
    const int jcol = wv * 16 + nloc;          // 0..111
    const int kt_h = jcol >> 5;
    const int jh   = jcol & 7;
    const int qh16 = ((jcol >> 3) & 3) * 16;  // lane' = b + qh16

    // --- x loader mapping: 256 threads (waves 0-3), ONE element each ---
    const int xb = u >> 4;                    // batch 0..15
    const int xc = u & 15;                    // channel 0..15
    const size_t xbase = (size_t)(b0 + xb) * (T_LEN * C_IN) + xc;
    const int ltx = xb + 16 * (((HH + xc) >> 3) & 3);   // A-frag lane for k=112+xc
    const int jx  = xc & 7;

    float xval;
    if (u < 256) {
        xval = x[xbase];                      // x at t=0 -> parity 0
        vbuf[0][3][ltx][jx] = (_Float16)xval;
    }
    __syncthreads();

    float creg[4] = {0.f, 0.f, 0.f, 0.f};

    for (int step = 0; step < T_LEN; ++step) {
        const int p = step & 1;
        if (u < 256 && step + 1 < T_LEN)
            xval = x[xbase + (size_t)(step + 1) * C_IN];   // prefetch next x

        // A-fragments for this step (all 4 k-tiles, single plane)
        half8 ah[4];
        #pragma unroll
        for (int kt = 0; kt < 4; ++kt)
            ah[kt] = *(const half8*)&vbuf[p][kt][lane][0];

        // accumulator init = prescaled bias: MFMA output is the exp2 argument
        f32x4 ch[4];
        #pragma unroll
        for (int nt = 0; nt < 4; ++nt)
            ch[nt] = (f32x4){bpre[nt], bpre[nt], bpre[nt], bpre[nt]};

        float act[4][4];
        float thc[4];

        // nt-outer pipeline: gate nt's activation VALU overlaps gate nt+1's
        // MFMA issue; cell update (needs i,f,g) overlaps gate-o's MFMAs.
        MFMA_NT(0);
        MFMA_NT(1);  ACT_NT(0);
        MFMA_NT(2);  ACT_NT(1);
        MFMA_NT(3);  ACT_NT(2);
        #pragma unroll
        for (int r = 0; r < 4; ++r) {
            const float cn = fmaf(act[1][r], creg[r], act[0][r] * act[2][r]);
            creg[r] = cn;
            const float e2 = __builtin_amdgcn_exp2f(cn * (-2.f * L2E));
            thc[r] = fmaf(2.f, __builtin_amdgcn_rcpf(1.f + e2), -1.f);
        }
        ACT_NT(3);

        const bool last = (step + 1 == T_LEN);
        #pragma unroll
        for (int r = 0; r < 4; ++r) {
            const float hv = act[3][r] * thc[r];
            if (!last) {
                vbuf[1 - p][kt_h][q * 4 + r + qh16][jh] = (_Float16)hv;
            } else {
                hfinal[q * 4 + r][jcol] = hv;
            }
        }
        if (u < 256 && step + 1 < T_LEN)
            vbuf[1 - p][3][ltx][jx] = (_Float16)xval;
        __syncthreads();
    }

    // --- FC head ---
    if (u < NB * 6) {
        const int b = u / 6, o = u - b * 6;
        float a = b_fc[o];
        for (int j = 0; j < HH; ++j) a += hfinal[b][j] * W_fc[o * HH + j];
        out[(size_t)(b0 + b) * 6 + o] = tanhf(a);
    }
}

extern "C" void kernel_launch(void* const* d_in, const int* in_sizes, int n_in,
                              void* d_out, int out_size, void* d_ws, size_t ws_size,
                              hipStream_t stream) {
    const float* x     = (const float*)d_in[0];
    const float* gamma = (const float*)d_in[1];
    const float* beta  = (const float*)d_in[2];
    const float* W_ih  = (const float*)d_in[3];
    const float* W_hh  = (const float*)d_in[4];
    const float* b_ih  = (const float*)d_in[5];
    const float* b_hh  = (const float*)d_in[6];
    const float* W_fc  = (const float*)d_in[7];
    const float* b_fc  = (const float*)d_in[8];
    float* out = (float*)d_out;
    float* ws  = (float*)d_ws;

    stats_kernel<<<SBLK, STHR, 0, stream>>>(x, ws);
    lstm_kernel<<<B_TOT / NB, 448, 0, stream>>>(x, gamma, beta, W_ih, W_hh,
                                                b_ih, b_hh, W_fc, b_fc, ws, out);
}

// Round 8
// 256.489 us; speedup vs baseline: 1.3515x; 1.0128x over previous
//
#include <hip/hip_runtime.h>
#include <math.h>

#define B_TOT 4096
#define T_LEN 200
#define C_IN  16
#define HH    112
#define G4    448
#define NB    16      // batches per block (= MFMA M)
#define EPS   1e-5f
#define SBLK  256     // stats kernel blocks
#define STHR  1024    // stats kernel threads (16 waves: latency hiding)

typedef _Float16 half8  __attribute__((ext_vector_type(8)));
typedef float    f32x4  __attribute__((ext_vector_type(4)));

#define L2E 1.4426950408889634f
#define FLUSH_MIN 6.103515625e-05f   // fp16 min normal

// fp16 cast with denormal flush — one-time weight conversion only.
__device__ __forceinline__ _Float16 to16f(float v) {
    _Float16 h = (_Float16)v;
    if (__builtin_fabsf(v) < FLUSH_MIN) h = (_Float16)0.0f;
    return h;
}

// ---------------- Kernel 1: deterministic per-channel partial sums ----------------
// 256 blocks x 1024 threads (16 waves/CU) -> latency hidden, ~10 us.
__global__ __launch_bounds__(STHR) void stats_kernel(const float* __restrict__ x,
                                                     float* __restrict__ ws) {
    __shared__ float sm[16][4][8];
    const int tid = threadIdx.x;
    const float4* __restrict__ x4 = (const float4*)x;
    const int total  = B_TOT * T_LEN * C_IN / 4;
    const int stride = SBLK * STHR;
    const int i0 = blockIdx.x * STHR + tid;

    float s0=0.f,s1=0.f,s2=0.f,s3=0.f;
    float q0=0.f,q1=0.f,q2=0.f,q3=0.f;
    for (int i = i0; i < total; i += stride) {
        float4 v = x4[i];
        s0 += v.x; q0 += v.x*v.x;
        s1 += v.y; q1 += v.y*v.y;
        s2 += v.z; q2 += v.z*v.z;
        s3 += v.w; q3 += v.w*v.w;
    }
    #pragma unroll
    for (int off = 4; off < 64; off <<= 1) {
        s0 += __shfl_xor(s0, off); q0 += __shfl_xor(q0, off);
        s1 += __shfl_xor(s1, off); q1 += __shfl_xor(q1, off);
        s2 += __shfl_xor(s2, off); q2 += __shfl_xor(q2, off);
        s3 += __shfl_xor(s3, off); q3 += __shfl_xor(q3, off);
    }
    const int lane = tid & 63, wave = tid >> 6;
    if (lane < 4) {
        sm[wave][lane][0] = s0; sm[wave][lane][1] = s1;
        sm[wave][lane][2] = s2; sm[wave][lane][3] = s3;
        sm[wave][lane][4] = q0; sm[wave][lane][5] = q1;
        sm[wave][lane][6] = q2; sm[wave][lane][7] = q3;
    }
    __syncthreads();
    if (tid < 32) {
        const int ch = tid & 15, sq = tid >> 4;
        const int grp = ch >> 2, comp = ch & 3;
        float a = 0.f;
        #pragma unroll
        for (int wv = 0; wv < 16; wv++) a += sm[wv][grp][sq * 4 + comp];
        ws[blockIdx.x * 32 + tid] = a;
    }
}

// ---------------- Kernel 2: MFMA LSTM, one barrier/step ----------------
// 256 blocks x 448 threads (7 waves). Wave w owns the FOUR GATE TILES of
// j-tile w. Cell update in-lane, c in registers. v_t = [h;x] in LDS,
// A-fragment order, single fp16 plane. Weights k1-prescaled fp16.
// Round-8 trims (all bitwise-identical math):
//  - first MFMA per gate takes persistent cinit (prescaled bias) as C
//    operand -> deletes 16 acc-init v_movs/step.
//  - gate order g,i,f,o: cell+tanh(c) trans chain hides under MFMA_o issue.
//  - ALL x staging moved to wave 3 (the lone wave on SIMD3): 4 elems/lane,
//    wave-uniform branches; waves 0-2,4-6 carry zero x overhead.

#define MFMA_NT(nt) do {                                                             \
    ch[nt] = __builtin_amdgcn_mfma_f32_16x16x32_f16(ah[0], wHI[nt][0], cinit[nt], 0, 0, 0); \
    _Pragma("unroll")                                                                \
    for (int kt = 1; kt < 4; ++kt)                                                   \
        ch[nt] = __builtin_amdgcn_mfma_f32_16x16x32_f16(ah[kt], wHI[nt][kt], ch[nt], 0, 0, 0); \
} while (0)

#define ACT_NT(nt) do {                                                              \
    _Pragma("unroll")                                                                \
    for (int r = 0; r < 4; ++r) {                                                    \
        const float e_  = __builtin_amdgcn_exp2f(ch[nt][r]);                         \
        const float rr_ = __builtin_amdgcn_rcpf(1.f + e_);                           \
        act[nt][r] = ((nt) == 2) ? fmaf(2.f, rr_, -1.f) : rr_;                       \
    }                                                                                \
} while (0)

__global__ __launch_bounds__(448, 2) void lstm_kernel(
    const float* __restrict__ x,
    const float* __restrict__ gamma, const float* __restrict__ beta,
    const float* __restrict__ W_ih,  const float* __restrict__ W_hh,
    const float* __restrict__ b_ih,  const float* __restrict__ b_hh,
    const float* __restrict__ W_fc,  const float* __restrict__ b_fc,
    const float* __restrict__ ws,    float* __restrict__ out)
{
    __shared__ float stats_s[32];
    __shared__ float scale_s[16], shift_s[16];
    __shared__ __align__(16) _Float16 vbuf[2][4][64][8]; // [parity][kt][lane][8]
    __shared__ __align__(16) float hfinal[NB][HH];

    const int u    = threadIdx.x;
    const int lane = u & 63;
    const int wv   = u >> 6;          // wave = j-tile 0..6
    const int nloc = lane & 15;
    const int q    = lane >> 4;       // 0..3
    const int b0   = blockIdx.x * NB;

    // --- BN stats (deterministic fixed-order reduction) ---
    if (u < 32) {
        float a = 0.f;
        for (int blk = 0; blk < SBLK; ++blk) a += ws[blk * 32 + u];
        stats_s[u] = a;
    }
    __syncthreads();
    if (u < 16) {
        const float N = (float)B_TOT * (float)T_LEN;
        const float mean = stats_s[u] / N;
        const float var  = stats_s[16 + u] / N - mean * mean;
        const float sc   = gamma[u] * rsqrtf(var + EPS);
        scale_s[u] = sc;
        shift_s[u] = beta[u] - mean * sc;
    }
    for (int i = u; i < (int)(sizeof(vbuf) / 4); i += G4) ((int*)vbuf)[i] = 0;
    __syncthreads();

    // --- Register-resident weight fragments (one-time, fp16, k1-prescaled) ---
    half8 wHI[4][4];
    f32x4 cinit[4];                   // persistent C operand: k1-prescaled bias
    #pragma unroll
    for (int nt = 0; nt < 4; ++nt) {  // nt == gate index
        const int n = nt * HH + wv * 16 + nloc;
        const float mg = (nt == 2) ? 2.f : 1.f;
        const float k1 = -mg * L2E;
        #pragma unroll
        for (int kt = 0; kt < 4; ++kt) {
            const int kb = kt * 32 + q * 8;    // never straddles k=112
            float wtmp[8];
            if (kb < HH) {
                float4 aa = *(const float4*)&W_hh[n * HH + kb];
                float4 bb = *(const float4*)&W_hh[n * HH + kb + 4];
                wtmp[0]=aa.x; wtmp[1]=aa.y; wtmp[2]=aa.z; wtmp[3]=aa.w;
                wtmp[4]=bb.x; wtmp[5]=bb.y; wtmp[6]=bb.z; wtmp[7]=bb.w;
            } else {
                const int c0 = kb - HH;
                float4 aa = *(const float4*)&W_ih[n * C_IN + c0];
                float4 bb = *(const float4*)&W_ih[n * C_IN + c0 + 4];
                wtmp[0]=aa.x*scale_s[c0+0]; wtmp[1]=aa.y*scale_s[c0+1];
                wtmp[2]=aa.z*scale_s[c0+2]; wtmp[3]=aa.w*scale_s[c0+3];
                wtmp[4]=bb.x*scale_s[c0+4]; wtmp[5]=bb.y*scale_s[c0+5];
                wtmp[6]=bb.z*scale_s[c0+6]; wtmp[7]=bb.w*scale_s[c0+7];
            }
            #pragma unroll
            for (int jj = 0; jj < 8; ++jj) wHI[nt][kt][jj] = to16f(k1 * wtmp[jj]);
        }
        float bb2 = b_ih[n] + b_hh[n];
        #pragma unroll
        for (int c = 0; c < C_IN; ++c) bb2 += W_ih[n * C_IN + c] * shift_s[c];
        const float bp = bb2 * k1;
        cinit[nt] = (f32x4){bp, bp, bp, bp};
    }

    // --- h write-back mapping (A-fragment address for column jcol) ---
    const int jcol = wv * 16 + nloc;          // 0..111
    const int kt_h = jcol >> 5;
    const int jh   = jcol & 7;
    const int qh16 = ((jcol >> 3) & 3) * 16;  // lane' = b + qh16

    // --- x staging: wave 3 only (lone wave on SIMD3), 4 elements/lane ---
    // lane l: channel c = l&15, batches b = (l>>4)*4 + ii, ii = 0..3
    const bool xw  = (wv == 3);
    const int  xc  = lane & 15;
    const int  xb4 = (lane >> 4) * 4;         // base batch for this lane
    const size_t xg0 = (size_t)(b0 + xb4) * (T_LEN * C_IN) + xc;
    const int  xlo = 16 * (((HH + xc) >> 3) & 3);   // A-frag lane group for k=112+xc
    const int  jx  = xc & 7;

    if (xw) {
        #pragma unroll
        for (int ii = 0; ii < 4; ++ii) {
            const float v = x[xg0 + (size_t)ii * (T_LEN * C_IN)];
            vbuf[0][3][xb4 + ii + xlo][jx] = (_Float16)v;
        }
    }
    __syncthreads();

    float creg[4] = {0.f, 0.f, 0.f, 0.f};

    for (int step = 0; step < T_LEN; ++step) {
        const int p = step & 1;

        // wave-3 x prefetch for t+1 (hidden under this step's compute)
        float xv0, xv1, xv2, xv3;
        if (xw && step + 1 < T_LEN) {
            const size_t o = xg0 + (size_t)(step + 1) * C_IN;
            xv0 = x[o];
            xv1 = x[o + 1 * (T_LEN * C_IN)];
            xv2 = x[o + 2 * (T_LEN * C_IN)];
            xv3 = x[o + 3 * (T_LEN * C_IN)];
        }

        // A-fragments for this step (all 4 k-tiles, single plane)
        half8 ah[4];
        #pragma unroll
        for (int kt = 0; kt < 4; ++kt)
            ah[kt] = *(const half8*)&vbuf[p][kt][lane][0];

        f32x4 ch[4];
        float act[4][4];
        float thc[4];

        // g-first pipeline: ACT_g early so the cell+tanh(c) trans chain
        // (needs i,f,g) hides under MFMA_o's issue window; only ACT_o + h
        // remain as serial tail.
        MFMA_NT(2);              // g
        MFMA_NT(0);  ACT_NT(2);  // i  | act_g
        MFMA_NT(1);  ACT_NT(0);  // f  | act_i
        MFMA_NT(3);  ACT_NT(1);  // o  | act_f
        #pragma unroll
        for (int r = 0; r < 4; ++r) {
            const float cn = fmaf(act[1][r], creg[r], act[0][r] * act[2][r]);
            creg[r] = cn;
            const float e2 = __builtin_amdgcn_exp2f(cn * (-2.f * L2E));
            thc[r] = fmaf(2.f, __builtin_amdgcn_rcpf(1.f + e2), -1.f);
        }
        ACT_NT(3);               // act_o (after MFMA_o drain)

        const bool last = (step + 1 == T_LEN);
        #pragma unroll
        for (int r = 0; r < 4; ++r) {
            const float hv = act[3][r] * thc[r];
            if (!last) {
                vbuf[1 - p][kt_h][q * 4 + r + qh16][jh] = (_Float16)hv;
            } else {
                hfinal[q * 4 + r][jcol] = hv;
            }
        }
        if (xw && step + 1 < T_LEN) {
            vbuf[1 - p][3][xb4 + 0 + xlo][jx] = (_Float16)xv0;
            vbuf[1 - p][3][xb4 + 1 + xlo][jx] = (_Float16)xv1;
            vbuf[1 - p][3][xb4 + 2 + xlo][jx] = (_Float16)xv2;
            vbuf[1 - p][3][xb4 + 3 + xlo][jx] = (_Float16)xv3;
        }
        __syncthreads();
    }

    // --- FC head ---
    if (u < NB * 6) {
        const int b = u / 6, o = u - b * 6;
        float a = b_fc[o];
        for (int j = 0; j < HH; ++j) a += hfinal[b][j] * W_fc[o * HH + j];
        out[(size_t)(b0 + b) * 6 + o] = tanhf(a);
    }
}

extern "C" void kernel_launch(void* const* d_in, const int* in_sizes, int n_in,
                              void* d_out, int out_size, void* d_ws, size_t ws_size,
                              hipStream_t stream) {
    const float* x     = (const float*)d_in[0];
    const float* gamma = (const float*)d_in[1];
    const float* beta  = (const float*)d_in[2];
    const float* W_ih  = (const float*)d_in[3];
    const float* W_hh  = (const float*)d_in[4];
    const float* b_ih  = (const float*)d_in[5];
    const float* b_hh  = (const float*)d_in[6];
    const float* W_fc  = (const float*)d_in[7];
    const float* b_fc  = (const float*)d_in[8];
    float* out = (float*)d_out;
    float* ws  = (float*)d_ws;

    stats_kernel<<<SBLK, STHR, 0, stream>>>(x, ws);
    lstm_kernel<<<B_TOT / NB, 448, 0, stream>>>(x, gamma, beta, W_ih, W_hh,
                                                b_ih, b_hh, W_fc, b_fc, ws, out);
}